// Round 16
// baseline (161.782 us; speedup 1.0000x reference)
//
#include <hip/hip_runtime.h>

#define NN 50000
#define NE 600000
#define NG 64
#define SCAN_T 1024
#define SCAN_NB ((NN + SCAN_T - 1) / SCAN_T)  // 49
#define SCANX_NB 64                           // 49 scan blocks + 15 aux blocks
#define GEMM_NB ((NN + 127) / 128)            // 391
#define EPB ((NE + GEMM_NB - 1) / GEMM_NB)    // 1535 edges per gemm block

typedef unsigned int uint_t;
typedef unsigned short ushort_t;
typedef __attribute__((ext_vector_type(8))) short bf16x8;
typedef __attribute__((ext_vector_type(4))) float f32x4;

__device__ __forceinline__ ushort_t f2bf(float x) {
    uint_t u = __builtin_bit_cast(uint_t, x);
    u = (u + 0x7FFFu + ((u >> 16) & 1u)) >> 16;  // round-to-nearest-even
    return (ushort_t)u;
}
__device__ __forceinline__ float bf_lo(uint_t p) {
    uint_t v = p << 16; return __builtin_bit_cast(float, v);
}
__device__ __forceinline__ float bf_hi(uint_t p) {
    uint_t v = p & 0xFFFF0000u; return __builtin_bit_cast(float, v);
}

// ---------------- prep: zero deg + scan flags ----------------
__global__ void k_prep(int* __restrict__ deg, int* __restrict__ scanflags) {
    int i = blockIdx.x * blockDim.x + threadIdx.x;
    if (i < NN) deg[i] = 0;
    if (i < SCANX_NB) scanflags[i] = 0;  // MSB clear = not published
}

__global__ void k_hist(const int* __restrict__ dst, int* __restrict__ deg) {
    int e = blockIdx.x * blockDim.x + threadIdx.x;
    if (e < NE) atomicAdd(&deg[dst[e]], 1);
}

// ---------------- single-pass scan (aggregate lookback) + aux prep ----------------
__global__ __launch_bounds__(SCAN_T) void k_scanx(const int* __restrict__ deg,
                                                  const float* __restrict__ W1,
                                                  const float* __restrict__ W2,
                                                  int* __restrict__ scanflags,
                                                  int* __restrict__ rowptr,
                                                  int* __restrict__ cursor,
                                                  float* __restrict__ dinv,
                                                  ushort_t* __restrict__ W1t,
                                                  ushort_t* __restrict__ W2t,
                                                  float* __restrict__ psum) {
    const int b = blockIdx.x;
    const int tid = threadIdx.x;

    if (b >= SCAN_NB) {  // aux blocks: 15 x 1024 threads
        int idx = (b - SCAN_NB) * SCAN_T + tid;
        for (int i = idx; i < 128 * 128; i += (SCANX_NB - SCAN_NB) * SCAN_T) {
            int k = i >> 7, n = i & 127;
            W1t[n * 128 + k] = f2bf(W1[i]);
        }
        if (idx < 128 * 64) {
            int k = idx >> 6, n = idx & 63;
            W2t[n * 128 + k] = f2bf(W2[idx]);
        }
        if (idx < NG * 64) psum[idx] = 0.f;
        return;
    }

    __shared__ int s[SCAN_T];
    __shared__ int offs_s;
    const int i = b * SCAN_T + tid;
    const int v = (i < NN) ? deg[i] : 0;
    s[tid] = v;
    __syncthreads();
    for (int off = 1; off < SCAN_T; off <<= 1) {
        int u = (tid >= off) ? s[tid - off] : 0;
        int cur = s[tid];
        __syncthreads();
        s[tid] = cur + u;
        __syncthreads();
    }
    if (tid == SCAN_T - 1) {
        __hip_atomic_store(&scanflags[b], s[SCAN_T - 1] | (int)0x80000000,
                           __ATOMIC_RELEASE, __HIP_MEMORY_SCOPE_AGENT);
    }
    if (tid < 64) {
        int w = 0;
        if (tid < b) {
            int f;
            do {
                f = __hip_atomic_load(&scanflags[tid], __ATOMIC_ACQUIRE,
                                      __HIP_MEMORY_SCOPE_AGENT);
            } while (!(f & (int)0x80000000));
            w = f & 0x7FFFFFFF;
        }
        for (int off = 32; off > 0; off >>= 1) w += __shfl_down(w, off);
        if (tid == 0) offs_s = w;
    }
    __syncthreads();

    if (i < NN) {
        int ex = offs_s + s[tid] - v;  // exclusive prefix
        rowptr[i] = ex;
        cursor[i] = ex;
        dinv[i] = rsqrtf((float)(v + 1));
    }
    if (i == 0) rowptr[NN] = NE;
}

// ---------------- bf16 MFMA GEMM 1 + fused CSR edge-scatter tail ----------------
// Hb = bf16((X @ W1) * dinv); then this block scatters its slice of edges.
// Both depend only on k_scanx; co-residency hides scatter latency under MFMA.
__global__ __launch_bounds__(256) void k_gemm_scatter(const float* __restrict__ X,
                                                      const ushort_t* __restrict__ Wt,
                                                      const float* __restrict__ dinv,
                                                      const int* __restrict__ src,
                                                      const int* __restrict__ dst,
                                                      int* __restrict__ cursor,
                                                      int* __restrict__ csr_src,
                                                      ushort_t* __restrict__ Hb) {
    __shared__ ushort_t xs[128 * 128];   // 32 KB
    __shared__ ushort_t ws[128 * 128];   // 32 KB
    const int tid = threadIdx.x;
    const int row0 = blockIdx.x * 128;

    for (int idx = tid; idx < 128 * 32; idx += 256) {   // X: f32 -> bf16
        int r = idx >> 5, c4 = idx & 31;
        int row = row0 + r;
        float4 v = make_float4(0.f, 0.f, 0.f, 0.f);
        if (row < NN) v = ((const float4*)X)[(long)row * 32 + c4];
        ushort4 o;
        o.x = f2bf(v.x); o.y = f2bf(v.y); o.z = f2bf(v.z); o.w = f2bf(v.w);
        uint_t byte = (uint_t)(r * 256 + c4 * 8) ^ (uint_t)((r & 7) << 4);
        *(ushort4*)((char*)xs + byte) = o;
    }
    for (int idx = tid; idx < 128 * 16; idx += 256) {   // Wt (bf16)
        int n = idx >> 4, c16 = idx & 15;
        uint4 v = ((const uint4*)Wt)[idx];
        uint_t byte = (uint_t)(n * 256 + c16 * 16) ^ (uint_t)((n & 7) << 4);
        *(uint4*)((char*)ws + byte) = v;
    }
    __syncthreads();

    const int w = tid >> 6;
    const int l = tid & 63;
    const int m0 = (w >> 1) * 4;
    const int n0 = (w & 1) * 4;
    const int lr = l & 15;
    const int kg = l >> 4;

    f32x4 acc[4][4] = {};
    for (int kk = 0; kk < 4; ++kk) {
        const int kb = kk * 64 + kg * 16;
        bf16x8 a[4], b[4];
#pragma unroll
        for (int m = 0; m < 4; ++m) {
            int r = (m0 + m) * 16 + lr;
            uint_t byte = (uint_t)(r * 256 + kb) ^ (uint_t)((r & 7) << 4);
            a[m] = *(const bf16x8*)((const char*)xs + byte);
        }
#pragma unroll
        for (int n = 0; n < 4; ++n) {
            int r = (n0 + n) * 16 + lr;
            uint_t byte = (uint_t)(r * 256 + kb) ^ (uint_t)((r & 7) << 4);
            b[n] = *(const bf16x8*)((const char*)ws + byte);
        }
#pragma unroll
        for (int m = 0; m < 4; ++m)
#pragma unroll
            for (int n = 0; n < 4; ++n)
                acc[m][n] = __builtin_amdgcn_mfma_f32_16x16x32_bf16(a[m], b[n], acc[m][n], 0, 0, 0);
    }

#pragma unroll
    for (int m = 0; m < 4; ++m) {
#pragma unroll
        for (int r = 0; r < 4; ++r) {
            int row = row0 + (m0 + m) * 16 + kg * 4 + r;
            if (row < NN) {
                float sc = dinv[row];
#pragma unroll
                for (int n = 0; n < 4; ++n) {
                    int col = (n0 + n) * 16 + lr;
                    Hb[(long)row * 128 + col] = f2bf(acc[m][n][r] * sc);
                }
            }
        }
    }

    // ---- fused scatter tail: this block's slice of edges ----
    const int e0 = blockIdx.x * EPB;
    const int e1 = (e0 + EPB < NE) ? e0 + EPB : NE;
    for (int e = e0 + tid; e < e1; e += 256) {
        int d = dst[e];
        int p = atomicAdd(&cursor[d], 1);
        csr_src[p] = src[e];
    }
}

// ---------------- fused agg1 + gemm2: G = bf16( relu(dd*aggHb + b1) @ W2 * dinv ) ----------------
__global__ __launch_bounds__(512) void k_agg1g2(const int* __restrict__ rowptr,
                                                const int* __restrict__ csr_src,
                                                const float* __restrict__ dinv,
                                                const ushort_t* __restrict__ Hb,
                                                const float* __restrict__ bias,
                                                const ushort_t* __restrict__ W2t,
                                                ushort_t* __restrict__ G) {
    constexpr int TPN = 8;            // 128 ch / 16 per thread
    constexpr int NPB = 64;           // nodes per block
    __shared__ ushort_t hsh[NPB * 128];  // 16 KB  h1 tile (swizzled)
    __shared__ ushort_t ws2[64 * 128];   // 16 KB  W2t (swizzled)
    const int tid = threadIdx.x;
    const int row0 = blockIdx.x * NPB;
    const int nodeLocal = tid / TPN;
    const int node = row0 + nodeLocal;
    const int lane = tid % TPN;          // 16 channels: [lane*16, lane*16+16)

    for (int idx = tid; idx < 64 * 16; idx += 512) {
        int n = idx >> 4, c16 = idx & 15;
        uint4 v = ((const uint4*)W2t)[idx];
        uint_t byte = (uint_t)(n * 256 + c16 * 16) ^ (uint_t)((n & 7) << 4);
        *(uint4*)((char*)ws2 + byte) = v;
    }

    float a[16];
    if (node < NN) {
        const float dd = dinv[node];
        const uint2* __restrict__ H2 = (const uint2*)Hb;  // uint2 = 4 bf16
        const long base = (long)node * 32;                // 32 uint2 per row
#pragma unroll
        for (int q = 0; q < 4; ++q) {                     // self term
            uint2 h = H2[base + lane * 4 + q];
            a[q * 4 + 0] = bf_lo(h.x); a[q * 4 + 1] = bf_hi(h.x);
            a[q * 4 + 2] = bf_lo(h.y); a[q * 4 + 3] = bf_hi(h.y);
        }
        const int beg = rowptr[node], end = rowptr[node + 1];
        int k = beg;
        const int n2 = beg + ((end - beg) & ~1);
        for (; k < n2; k += 2) {       // 2-edge unroll, 4 uint4 in flight
            long b0 = (long)csr_src[k] * 16 + lane * 2;     // uint4 index
            long b1 = (long)csr_src[k + 1] * 16 + lane * 2;
            uint4 h0 = ((const uint4*)Hb)[b0];
            uint4 h1 = ((const uint4*)Hb)[b0 + 1];
            uint4 h2 = ((const uint4*)Hb)[b1];
            uint4 h3 = ((const uint4*)Hb)[b1 + 1];
            a[0] += bf_lo(h0.x) + bf_lo(h2.x); a[1] += bf_hi(h0.x) + bf_hi(h2.x);
            a[2] += bf_lo(h0.y) + bf_lo(h2.y); a[3] += bf_hi(h0.y) + bf_hi(h2.y);
            a[4] += bf_lo(h0.z) + bf_lo(h2.z); a[5] += bf_hi(h0.z) + bf_hi(h2.z);
            a[6] += bf_lo(h0.w) + bf_lo(h2.w); a[7] += bf_hi(h0.w) + bf_hi(h2.w);
            a[8]  += bf_lo(h1.x) + bf_lo(h3.x); a[9]  += bf_hi(h1.x) + bf_hi(h3.x);
            a[10] += bf_lo(h1.y) + bf_lo(h3.y); a[11] += bf_hi(h1.y) + bf_hi(h3.y);
            a[12] += bf_lo(h1.z) + bf_lo(h3.z); a[13] += bf_hi(h1.z) + bf_hi(h3.z);
            a[14] += bf_lo(h1.w) + bf_lo(h3.w); a[15] += bf_hi(h1.w) + bf_hi(h3.w);
        }
        for (; k < end; ++k) {
            long b0 = (long)csr_src[k] * 16 + lane * 2;
            uint4 h0 = ((const uint4*)Hb)[b0];
            uint4 h1 = ((const uint4*)Hb)[b0 + 1];
            a[0] += bf_lo(h0.x); a[1] += bf_hi(h0.x);
            a[2] += bf_lo(h0.y); a[3] += bf_hi(h0.y);
            a[4] += bf_lo(h0.z); a[5] += bf_hi(h0.z);
            a[6] += bf_lo(h0.w); a[7] += bf_hi(h0.w);
            a[8]  += bf_lo(h1.x); a[9]  += bf_hi(h1.x);
            a[10] += bf_lo(h1.y); a[11] += bf_hi(h1.y);
            a[12] += bf_lo(h1.z); a[13] += bf_hi(h1.z);
            a[14] += bf_lo(h1.w); a[15] += bf_hi(h1.w);
        }
#pragma unroll
        for (int q = 0; q < 4; ++q) {
            float4 bb = *(const float4*)&bias[lane * 16 + q * 4];
            float v0 = fmaxf(a[q * 4 + 0] * dd + bb.x, 0.f);
            float v1 = fmaxf(a[q * 4 + 1] * dd + bb.y, 0.f);
            float v2 = fmaxf(a[q * 4 + 2] * dd + bb.z, 0.f);
            float v3 = fmaxf(a[q * 4 + 3] * dd + bb.w, 0.f);
            ushort4 o;
            o.x = f2bf(v0); o.y = f2bf(v1); o.z = f2bf(v2); o.w = f2bf(v3);
            uint_t byte = (uint_t)(nodeLocal * 256 + lane * 32 + q * 8)
                        ^ (uint_t)((nodeLocal & 7) << 4);
            *(ushort4*)((char*)hsh + byte) = o;
        }
    } else {
#pragma unroll
        for (int q = 0; q < 4; ++q) {
            ushort4 o = {0, 0, 0, 0};
            uint_t byte = (uint_t)(nodeLocal * 256 + lane * 32 + q * 8)
                        ^ (uint_t)((nodeLocal & 7) << 4);
            *(ushort4*)((char*)hsh + byte) = o;
        }
    }
    __syncthreads();

    const int w = tid >> 6;
    const int l = tid & 63;
    const int lr = l & 15;
    const int kg = l >> 4;
    const int mt = w >> 1;
    const int nt0 = (w & 1) * 2;

    f32x4 acc[2] = {};
    for (int kk = 0; kk < 4; ++kk) {
        const int kb = kk * 64 + kg * 16;
        int ra = mt * 16 + lr;
        uint_t ba = (uint_t)(ra * 256 + kb) ^ (uint_t)((ra & 7) << 4);
        bf16x8 afrag = *(const bf16x8*)((const char*)hsh + ba);
#pragma unroll
        for (int j = 0; j < 2; ++j) {
            int rb = (nt0 + j) * 16 + lr;
            uint_t bb = (uint_t)(rb * 256 + kb) ^ (uint_t)((rb & 7) << 4);
            bf16x8 bfrag = *(const bf16x8*)((const char*)ws2 + bb);
            acc[j] = __builtin_amdgcn_mfma_f32_16x16x32_bf16(afrag, bfrag, acc[j], 0, 0, 0);
        }
    }

    float sc[4];
    int rowb = row0 + mt * 16 + kg * 4;
#pragma unroll
    for (int r = 0; r < 4; ++r) sc[r] = (rowb + r < NN) ? dinv[rowb + r] : 0.f;
#pragma unroll
    for (int j = 0; j < 2; ++j) {
        int col = (nt0 + j) * 16 + lr;
#pragma unroll
        for (int r = 0; r < 4; ++r) {
            int row = rowb + r;
            if (row < NN) G[(long)row * 64 + col] = f2bf(acc[j][r] * sc[r]);
        }
    }
}

// ---------------- agg layer 2 (C=64) fused with pooling ----------------
__global__ __launch_bounds__(256) void k_agg2pool(const int* __restrict__ rowptr,
                                                  const int* __restrict__ csr_src,
                                                  const float* __restrict__ dinv,
                                                  const ushort_t* __restrict__ Gb,
                                                  const int* __restrict__ batch,
                                                  float* __restrict__ psum) {
    constexpr int TPN = 8;            // 64 ch / 8 per thread
    constexpr int NPB = 32;           // nodes per block
    const int nodeLocal = threadIdx.x / TPN;
    const int node = blockIdx.x * NPB + nodeLocal;
    const int lane = threadIdx.x % TPN;
    __shared__ float vsh[NPB][64 + 1];
    __shared__ int gsh[NPB];

    if (node < NN) {
        const float dd = dinv[node];
        const uint4* __restrict__ H4 = (const uint4*)Gb;

        float a0, a1, a2, a3, a4, a5, a6, a7;
        {
            uint4 sv = H4[(long)node * TPN + lane];
            a0 = bf_lo(sv.x); a1 = bf_hi(sv.x);
            a2 = bf_lo(sv.y); a3 = bf_hi(sv.y);
            a4 = bf_lo(sv.z); a5 = bf_hi(sv.z);
            a6 = bf_lo(sv.w); a7 = bf_hi(sv.w);
        }
        const int beg = rowptr[node], end = rowptr[node + 1];
        int k = beg;
        const int n4 = beg + ((end - beg) & ~3);
        for (; k < n4; k += 4) {
            int s0 = csr_src[k + 0];
            int s1 = csr_src[k + 1];
            int s2 = csr_src[k + 2];
            int s3 = csr_src[k + 3];
            uint4 h0 = H4[(long)s0 * TPN + lane];
            uint4 h1 = H4[(long)s1 * TPN + lane];
            uint4 h2 = H4[(long)s2 * TPN + lane];
            uint4 h3 = H4[(long)s3 * TPN + lane];
            a0 += (bf_lo(h0.x) + bf_lo(h1.x)) + (bf_lo(h2.x) + bf_lo(h3.x));
            a1 += (bf_hi(h0.x) + bf_hi(h1.x)) + (bf_hi(h2.x) + bf_hi(h3.x));
            a2 += (bf_lo(h0.y) + bf_lo(h1.y)) + (bf_lo(h2.y) + bf_lo(h3.y));
            a3 += (bf_hi(h0.y) + bf_hi(h1.y)) + (bf_hi(h2.y) + bf_hi(h3.y));
            a4 += (bf_lo(h0.z) + bf_lo(h1.z)) + (bf_lo(h2.z) + bf_lo(h3.z));
            a5 += (bf_hi(h0.z) + bf_hi(h1.z)) + (bf_hi(h2.z) + bf_hi(h3.z));
            a6 += (bf_lo(h0.w) + bf_lo(h1.w)) + (bf_lo(h2.w) + bf_lo(h3.w));
            a7 += (bf_hi(h0.w) + bf_hi(h1.w)) + (bf_hi(h2.w) + bf_hi(h3.w));
        }
        for (; k < end; ++k) {
            int s = csr_src[k];
            uint4 h = H4[(long)s * TPN + lane];
            a0 += bf_lo(h.x); a1 += bf_hi(h.x);
            a2 += bf_lo(h.y); a3 += bf_hi(h.y);
            a4 += bf_lo(h.z); a5 += bf_hi(h.z);
            a6 += bf_lo(h.w); a7 += bf_hi(h.w);
        }
        float* vp = &vsh[nodeLocal][lane * 8];
        vp[0] = a0 * dd; vp[1] = a1 * dd; vp[2] = a2 * dd; vp[3] = a3 * dd;
        vp[4] = a4 * dd; vp[5] = a5 * dd; vp[6] = a6 * dd; vp[7] = a7 * dd;
        if (lane == 0) gsh[nodeLocal] = batch[node];
    } else {
        if (lane == 0) gsh[nodeLocal] = -1;
    }
    __syncthreads();

    if (threadIdx.x < 64) {
        const int ch = threadIdx.x;
        float acc = 0.f;
        int gprev = -1;
        for (int n = 0; n < NPB; ++n) {
            int g = gsh[n];
            if (g != gprev) {
                if (gprev >= 0) unsafeAtomicAdd(&psum[gprev * 64 + ch], acc);
                acc = 0.f;
                gprev = g;
            }
            if (g >= 0) acc += vsh[n][ch];
        }
        if (gprev >= 0) unsafeAtomicAdd(&psum[gprev * 64 + ch], acc);
    }
}

// ---------------- finalize: out = psum/cnt + b2 ----------------
__global__ __launch_bounds__(64) void k_pool2(const float* __restrict__ psum,
                                              const int* __restrict__ batch,
                                              const float* __restrict__ b2,
                                              float* __restrict__ out) {
    const int g = blockIdx.x;
    const int ch = threadIdx.x;
    int beg, end;
    {
        int lo = 0, hi = NN;
        while (lo < hi) { int mid = (lo + hi) >> 1; if (batch[mid] < g) lo = mid + 1; else hi = mid; }
        beg = lo;
        lo = beg; hi = NN;
        while (lo < hi) { int mid = (lo + hi) >> 1; if (batch[mid] < g + 1) lo = mid + 1; else hi = mid; }
        end = lo;
    }
    int cnt = end - beg;
    out[g * 64 + ch] = (cnt > 0) ? (psum[g * 64 + ch] / (float)cnt + b2[ch]) : 0.f;
}

extern "C" void kernel_launch(void* const* d_in, const int* in_sizes, int n_in,
                              void* d_out, int out_size, void* d_ws, size_t ws_size,
                              hipStream_t stream) {
    const float* x  = (const float*)d_in[0];
    const float* W1 = (const float*)d_in[1];
    const float* b1 = (const float*)d_in[2];
    const float* W2 = (const float*)d_in[3];
    const float* b2 = (const float*)d_in[4];
    const int* ei   = (const int*)d_in[5];
    const int* src  = (const int*)ei;
    const int* dst  = (const int*)(ei + NE);
    const int* batch = (const int*)d_in[6];
    float* out = (float*)d_out;

    char* p = (char*)d_ws;
    int* deg       = (int*)p;          p += (size_t)NN * 4;
    int* rowptr    = (int*)p;          p += (size_t)(NN + 4) * 4;
    int* cursor    = (int*)p;          p += (size_t)NN * 4;
    int* csr_src   = (int*)p;          p += (size_t)NE * 4;
    int* scanflags = (int*)p;          p += (size_t)SCANX_NB * 4;
    float* dinv    = (float*)p;        p += (size_t)NN * 4;
    float* psum    = (float*)p;        p += (size_t)NG * 64 * 4;
    ushort_t* W1t  = (ushort_t*)p;     p += (size_t)128 * 128 * 2;
    ushort_t* W2t  = (ushort_t*)p;     p += (size_t)64 * 128 * 2;
    ushort_t* Hb   = (ushort_t*)p;     p += (size_t)NN * 128 * 2;   // gemm1 out (pre-scaled)
    ushort_t* Gb   = (ushort_t*)p;     p += (size_t)NN * 64 * 2;    // fused agg1+gemm2 out (pre-scaled)

    // ---- CSR build + prep (7 dispatches total) ----
    k_prep<<<(NN + 255) / 256, 256, 0, stream>>>(deg, scanflags);
    k_hist<<<(NE + 255) / 256, 256, 0, stream>>>(dst, deg);
    k_scanx<<<SCANX_NB, SCAN_T, 0, stream>>>(deg, W1, W2, scanflags, rowptr, cursor,
                                             dinv, W1t, W2t, psum);

    // ---- layer 1 gemm + fused edge-scatter (both depend only on scanx) ----
    k_gemm_scatter<<<GEMM_NB, 256, 0, stream>>>(x, W1t, dinv, src, dst, cursor,
                                                csr_src, Hb);

    // ---- fused: agg1 (+bias,relu) + gemm2 (128->64) ----
    k_agg1g2<<<(NN + 63) / 64, 512, 0, stream>>>(rowptr, csr_src, dinv, Hb, b1, W2t, Gb);

    // ---- layer 2 aggregate fused with pooling ----
    k_agg2pool<<<(NN + 31) / 32, 256, 0, stream>>>(rowptr, csr_src, dinv, Gb, batch, psum);

    // ---- finalize ----
    k_pool2<<<NG, 64, 0, stream>>>(psum, batch, b2, out);
}

// Round 17
// 153.573 us; speedup vs baseline: 1.0535x; 1.0535x over previous
//
#include <hip/hip_runtime.h>

#define NN 50000
#define NE 600000
#define NG 64
#define SCAN_T 1024
#define SCAN_NB ((NN + SCAN_T - 1) / SCAN_T)  // 49

typedef unsigned int uint_t;
typedef unsigned short ushort_t;
typedef __attribute__((ext_vector_type(8))) short bf16x8;
typedef __attribute__((ext_vector_type(4))) float f32x4;

__device__ __forceinline__ ushort_t f2bf(float x) {
    uint_t u = __builtin_bit_cast(uint_t, x);
    u = (u + 0x7FFFu + ((u >> 16) & 1u)) >> 16;  // round-to-nearest-even
    return (ushort_t)u;
}
__device__ __forceinline__ float bf_lo(uint_t p) {
    uint_t v = p << 16; return __builtin_bit_cast(float, v);
}
__device__ __forceinline__ float bf_hi(uint_t p) {
    uint_t v = p & 0xFFFF0000u; return __builtin_bit_cast(float, v);
}

// ---------------- prep: zero deg/psum + transpose/quantize W1,W2 ----------------
__global__ void k_prep(const float* __restrict__ W1, const float* __restrict__ W2,
                       int* __restrict__ deg, float* __restrict__ psum,
                       ushort_t* __restrict__ W1t, ushort_t* __restrict__ W2t) {
    int i = blockIdx.x * blockDim.x + threadIdx.x;
    if (i < NN) deg[i] = 0;
    if (i < NG * 64) psum[i] = 0.f;
    if (i < 128 * 128) {
        int k = i >> 7, n = i & 127;
        W1t[n * 128 + k] = f2bf(W1[i]);
    }
    if (i < 128 * 64) {
        int k = i >> 6, n = i & 63;
        W2t[n * 128 + k] = f2bf(W2[i]);
    }
}

__global__ void k_hist(const int* __restrict__ dst, int* __restrict__ deg) {
    int e = blockIdx.x * blockDim.x + threadIdx.x;
    if (e < NE) atomicAdd(&deg[dst[e]], 1);
}

// ---------------- scan stage 1: per-block sums ----------------
__global__ __launch_bounds__(SCAN_T) void k_scan1(const int* __restrict__ deg,
                                                  int* __restrict__ blockSums) {
    __shared__ int s[SCAN_T];
    int i = blockIdx.x * SCAN_T + threadIdx.x;
    s[threadIdx.x] = (i < NN) ? deg[i] : 0;
    __syncthreads();
    for (int off = SCAN_T / 2; off > 0; off >>= 1) {
        if (threadIdx.x < off) s[threadIdx.x] += s[threadIdx.x + off];
        __syncthreads();
    }
    if (threadIdx.x == 0) blockSums[blockIdx.x] = s[0];
}

// ---------------- scan stage 2+3 fused ----------------
__global__ __launch_bounds__(SCAN_T) void k_scan3(const int* __restrict__ deg,
                                                  const int* __restrict__ blockSums,
                                                  int* __restrict__ rowptr,
                                                  int* __restrict__ cursor,
                                                  float* __restrict__ dinv) {
    __shared__ int offs[64];
    __shared__ int s[SCAN_T];
    const int t = threadIdx.x;
    if (t < 64) {
        int orig = (t < SCAN_NB) ? blockSums[t] : 0;
        int v = orig;
        for (int off = 1; off < 64; off <<= 1) {
            int u = __shfl_up(v, off);
            if (t >= off) v += u;
        }
        offs[t] = v - orig;
    }
    const int i = blockIdx.x * SCAN_T + t;
    const int v = (i < NN) ? deg[i] : 0;
    s[t] = v;
    __syncthreads();
    for (int off = 1; off < SCAN_T; off <<= 1) {
        int u = (t >= off) ? s[t - off] : 0;
        int cur = s[t];
        __syncthreads();
        s[t] = cur + u;
        __syncthreads();
    }
    if (i < NN) {
        int ex = offs[blockIdx.x] + s[t] - v;
        rowptr[i] = ex;
        cursor[i] = ex;
        dinv[i] = rsqrtf((float)(v + 1));
    }
    if (i == 0) rowptr[NN] = NE;
}

__global__ void k_scatter(const int* __restrict__ src, const int* __restrict__ dst,
                          int* __restrict__ cursor, int* __restrict__ csr_src) {
    int e = blockIdx.x * blockDim.x + threadIdx.x;
    if (e >= NE) return;
    int d = dst[e];
    int p = atomicAdd(&cursor[d], 1);
    csr_src[p] = src[e];
}

// ---------------- bf16 MFMA GEMM 1: Hb = bf16((X @ W1) * dinv) ----------------
__global__ __launch_bounds__(256) void k_gemm_mfma(const float* __restrict__ X,
                                                   const ushort_t* __restrict__ Wt,
                                                   const float* __restrict__ dinv,
                                                   ushort_t* __restrict__ Hb) {
    __shared__ ushort_t xs[128 * 128];   // 32 KB
    __shared__ ushort_t ws[128 * 128];   // 32 KB
    const int tid = threadIdx.x;
    const int row0 = blockIdx.x * 128;

    for (int idx = tid; idx < 128 * 32; idx += 256) {   // X: f32 -> bf16
        int r = idx >> 5, c4 = idx & 31;
        int row = row0 + r;
        float4 v = make_float4(0.f, 0.f, 0.f, 0.f);
        if (row < NN) v = ((const float4*)X)[(long)row * 32 + c4];
        ushort4 o;
        o.x = f2bf(v.x); o.y = f2bf(v.y); o.z = f2bf(v.z); o.w = f2bf(v.w);
        uint_t byte = (uint_t)(r * 256 + c4 * 8) ^ (uint_t)((r & 7) << 4);
        *(ushort4*)((char*)xs + byte) = o;
    }
    for (int idx = tid; idx < 128 * 16; idx += 256) {   // Wt (bf16)
        int n = idx >> 4, c16 = idx & 15;
        uint4 v = ((const uint4*)Wt)[idx];
        uint_t byte = (uint_t)(n * 256 + c16 * 16) ^ (uint_t)((n & 7) << 4);
        *(uint4*)((char*)ws + byte) = v;
    }
    __syncthreads();

    const int w = tid >> 6;
    const int l = tid & 63;
    const int m0 = (w >> 1) * 4;
    const int n0 = (w & 1) * 4;
    const int lr = l & 15;
    const int kg = l >> 4;

    f32x4 acc[4][4] = {};
    for (int kk = 0; kk < 4; ++kk) {
        const int kb = kk * 64 + kg * 16;
        bf16x8 a[4], b[4];
#pragma unroll
        for (int m = 0; m < 4; ++m) {
            int r = (m0 + m) * 16 + lr;
            uint_t byte = (uint_t)(r * 256 + kb) ^ (uint_t)((r & 7) << 4);
            a[m] = *(const bf16x8*)((const char*)xs + byte);
        }
#pragma unroll
        for (int n = 0; n < 4; ++n) {
            int r = (n0 + n) * 16 + lr;
            uint_t byte = (uint_t)(r * 256 + kb) ^ (uint_t)((r & 7) << 4);
            b[n] = *(const bf16x8*)((const char*)ws + byte);
        }
#pragma unroll
        for (int m = 0; m < 4; ++m)
#pragma unroll
            for (int n = 0; n < 4; ++n)
                acc[m][n] = __builtin_amdgcn_mfma_f32_16x16x32_bf16(a[m], b[n], acc[m][n], 0, 0, 0);
    }

#pragma unroll
    for (int m = 0; m < 4; ++m) {
#pragma unroll
        for (int r = 0; r < 4; ++r) {
            int row = row0 + (m0 + m) * 16 + kg * 4 + r;
            if (row < NN) {
                float sc = dinv[row];
#pragma unroll
                for (int n = 0; n < 4; ++n) {
                    int col = (n0 + n) * 16 + lr;
                    Hb[(long)row * 128 + col] = f2bf(acc[m][n][r] * sc);
                }
            }
        }
    }
}

// ---------------- fused agg1 + gemm2: G = bf16( relu(dd*aggHb + b1) @ W2 * dinv ) ----------------
// Block: 256 thr, 32 nodes. Phase 1: gather-agg h1 (TPN=8, 16 ch/thread) -> LDS bf16.
// Phase 2: 32x64x128 MFMA vs W2t (staged in LDS). Output G bf16 (pre-scaled by dinv).
__global__ __launch_bounds__(256) void k_agg1g2(const int* __restrict__ rowptr,
                                                const int* __restrict__ csr_src,
                                                const float* __restrict__ dinv,
                                                const ushort_t* __restrict__ Hb,
                                                const float* __restrict__ bias,
                                                const ushort_t* __restrict__ W2t,
                                                ushort_t* __restrict__ G) {
    constexpr int TPN = 8;            // 128 ch / 16 per thread
    constexpr int NPB = 32;           // nodes per block
    __shared__ ushort_t hsh[NPB * 128];  // 8 KB  h1 tile (swizzled)
    __shared__ ushort_t ws2[64 * 128];   // 16 KB W2t (swizzled)
    const int tid = threadIdx.x;
    const int row0 = blockIdx.x * NPB;
    const int nodeLocal = tid / TPN;
    const int node = row0 + nodeLocal;
    const int lane = tid % TPN;          // 16 channels: [lane*16, lane*16+16)

    // stage W2t (no dependency on gather)
    for (int idx = tid; idx < 64 * 16; idx += 256) {
        int n = idx >> 4, c16 = idx & 15;
        uint4 v = ((const uint4*)W2t)[idx];
        uint_t byte = (uint_t)(n * 256 + c16 * 16) ^ (uint_t)((n & 7) << 4);
        *(uint4*)((char*)ws2 + byte) = v;
    }

    // phase 1: edge-gather aggregation (16 f32 acc per thread)
    float a[16];
    if (node < NN) {
        const float dd = dinv[node];
        const uint2* __restrict__ H2 = (const uint2*)Hb;  // uint2 = 4 bf16
        const long base = (long)node * 32;                // 32 uint2 per row
        // self term
#pragma unroll
        for (int q = 0; q < 4; ++q) {
            uint2 h = H2[base + lane * 4 + q];
            a[q * 4 + 0] = bf_lo(h.x); a[q * 4 + 1] = bf_hi(h.x);
            a[q * 4 + 2] = bf_lo(h.y); a[q * 4 + 3] = bf_hi(h.y);
        }
        const int beg = rowptr[node], end = rowptr[node + 1];
        int k = beg;
        const int n2 = beg + ((end - beg) & ~1);
        for (; k < n2; k += 2) {       // 2-edge unroll, 4 uint4 in flight
            long b0 = (long)csr_src[k] * 16 + lane * 2;     // uint4 index
            long b1 = (long)csr_src[k + 1] * 16 + lane * 2;
            uint4 h0 = ((const uint4*)Hb)[b0];
            uint4 h1 = ((const uint4*)Hb)[b0 + 1];
            uint4 h2 = ((const uint4*)Hb)[b1];
            uint4 h3 = ((const uint4*)Hb)[b1 + 1];
            a[0] += bf_lo(h0.x) + bf_lo(h2.x); a[1] += bf_hi(h0.x) + bf_hi(h2.x);
            a[2] += bf_lo(h0.y) + bf_lo(h2.y); a[3] += bf_hi(h0.y) + bf_hi(h2.y);
            a[4] += bf_lo(h0.z) + bf_lo(h2.z); a[5] += bf_hi(h0.z) + bf_hi(h2.z);
            a[6] += bf_lo(h0.w) + bf_lo(h2.w); a[7] += bf_hi(h0.w) + bf_hi(h2.w);
            a[8]  += bf_lo(h1.x) + bf_lo(h3.x); a[9]  += bf_hi(h1.x) + bf_hi(h3.x);
            a[10] += bf_lo(h1.y) + bf_lo(h3.y); a[11] += bf_hi(h1.y) + bf_hi(h3.y);
            a[12] += bf_lo(h1.z) + bf_lo(h3.z); a[13] += bf_hi(h1.z) + bf_hi(h3.z);
            a[14] += bf_lo(h1.w) + bf_lo(h3.w); a[15] += bf_hi(h1.w) + bf_hi(h3.w);
        }
        for (; k < end; ++k) {
            long b0 = (long)csr_src[k] * 16 + lane * 2;
            uint4 h0 = ((const uint4*)Hb)[b0];
            uint4 h1 = ((const uint4*)Hb)[b0 + 1];
            a[0] += bf_lo(h0.x); a[1] += bf_hi(h0.x);
            a[2] += bf_lo(h0.y); a[3] += bf_hi(h0.y);
            a[4] += bf_lo(h0.z); a[5] += bf_hi(h0.z);
            a[6] += bf_lo(h0.w); a[7] += bf_hi(h0.w);
            a[8]  += bf_lo(h1.x); a[9]  += bf_hi(h1.x);
            a[10] += bf_lo(h1.y); a[11] += bf_hi(h1.y);
            a[12] += bf_lo(h1.z); a[13] += bf_hi(h1.z);
            a[14] += bf_lo(h1.w); a[15] += bf_hi(h1.w);
        }
        // h1 = relu(dd*acc + b1) -> LDS (bf16, swizzled)
#pragma unroll
        for (int q = 0; q < 4; ++q) {
            float4 bb = *(const float4*)&bias[lane * 16 + q * 4];
            float v0 = fmaxf(a[q * 4 + 0] * dd + bb.x, 0.f);
            float v1 = fmaxf(a[q * 4 + 1] * dd + bb.y, 0.f);
            float v2 = fmaxf(a[q * 4 + 2] * dd + bb.z, 0.f);
            float v3 = fmaxf(a[q * 4 + 3] * dd + bb.w, 0.f);
            ushort4 o;
            o.x = f2bf(v0); o.y = f2bf(v1); o.z = f2bf(v2); o.w = f2bf(v3);
            uint_t byte = (uint_t)(nodeLocal * 256 + lane * 32 + q * 8)
                        ^ (uint_t)((nodeLocal & 7) << 4);
            *(ushort4*)((char*)hsh + byte) = o;
        }
    } else {
        // zero-fill invalid rows so MFMA reads are finite
#pragma unroll
        for (int q = 0; q < 4; ++q) {
            ushort4 o = {0, 0, 0, 0};
            uint_t byte = (uint_t)(nodeLocal * 256 + lane * 32 + q * 8)
                        ^ (uint_t)((nodeLocal & 7) << 4);
            *(ushort4*)((char*)hsh + byte) = o;
        }
    }
    __syncthreads();

    // phase 2: 32x64x128 MFMA. wave w: mtile w>>1 (16 rows), ntiles (w&1)*2+{0,1}
    const int w = tid >> 6;
    const int l = tid & 63;
    const int lr = l & 15;
    const int kg = l >> 4;
    const int mt = w >> 1;
    const int nt0 = (w & 1) * 2;

    f32x4 acc[2] = {};
    for (int kk = 0; kk < 4; ++kk) {
        const int kb = kk * 64 + kg * 16;
        int ra = mt * 16 + lr;
        uint_t ba = (uint_t)(ra * 256 + kb) ^ (uint_t)((ra & 7) << 4);
        bf16x8 afrag = *(const bf16x8*)((const char*)hsh + ba);
#pragma unroll
        for (int j = 0; j < 2; ++j) {
            int rb = (nt0 + j) * 16 + lr;
            uint_t bb = (uint_t)(rb * 256 + kb) ^ (uint_t)((rb & 7) << 4);
            bf16x8 bfrag = *(const bf16x8*)((const char*)ws2 + bb);
            acc[j] = __builtin_amdgcn_mfma_f32_16x16x32_bf16(afrag, bfrag, acc[j], 0, 0, 0);
        }
    }

    // epilogue: row = row0 + mt*16 + kg*4 + r, col = (nt0+j)*16 + lr
    float sc[4];
    int rowb = row0 + mt * 16 + kg * 4;
#pragma unroll
    for (int r = 0; r < 4; ++r) sc[r] = (rowb + r < NN) ? dinv[rowb + r] : 0.f;
#pragma unroll
    for (int j = 0; j < 2; ++j) {
        int col = (nt0 + j) * 16 + lr;
#pragma unroll
        for (int r = 0; r < 4; ++r) {
            int row = rowb + r;
            if (row < NN) G[(long)row * 64 + col] = f2bf(acc[j][r] * sc[r]);
        }
    }
}

// ---------------- agg layer 2 (C=64) fused with pooling ----------------
__global__ __launch_bounds__(256) void k_agg2pool(const int* __restrict__ rowptr,
                                                  const int* __restrict__ csr_src,
                                                  const float* __restrict__ dinv,
                                                  const ushort_t* __restrict__ Gb,
                                                  const int* __restrict__ batch,
                                                  float* __restrict__ psum) {
    constexpr int TPN = 8;            // 64 ch / 8 per thread
    constexpr int NPB = 32;           // nodes per block
    const int nodeLocal = threadIdx.x / TPN;
    const int node = blockIdx.x * NPB + nodeLocal;
    const int lane = threadIdx.x % TPN;
    __shared__ float vsh[NPB][64 + 1];
    __shared__ int gsh[NPB];

    if (node < NN) {
        const float dd = dinv[node];
        const uint4* __restrict__ H4 = (const uint4*)Gb;

        float a0, a1, a2, a3, a4, a5, a6, a7;
        {
            uint4 sv = H4[(long)node * TPN + lane];
            a0 = bf_lo(sv.x); a1 = bf_hi(sv.x);
            a2 = bf_lo(sv.y); a3 = bf_hi(sv.y);
            a4 = bf_lo(sv.z); a5 = bf_hi(sv.z);
            a6 = bf_lo(sv.w); a7 = bf_hi(sv.w);
        }
        const int beg = rowptr[node], end = rowptr[node + 1];
        int k = beg;
        const int n4 = beg + ((end - beg) & ~3);
        for (; k < n4; k += 4) {
            int s0 = csr_src[k + 0];
            int s1 = csr_src[k + 1];
            int s2 = csr_src[k + 2];
            int s3 = csr_src[k + 3];
            uint4 h0 = H4[(long)s0 * TPN + lane];
            uint4 h1 = H4[(long)s1 * TPN + lane];
            uint4 h2 = H4[(long)s2 * TPN + lane];
            uint4 h3 = H4[(long)s3 * TPN + lane];
            a0 += (bf_lo(h0.x) + bf_lo(h1.x)) + (bf_lo(h2.x) + bf_lo(h3.x));
            a1 += (bf_hi(h0.x) + bf_hi(h1.x)) + (bf_hi(h2.x) + bf_hi(h3.x));
            a2 += (bf_lo(h0.y) + bf_lo(h1.y)) + (bf_lo(h2.y) + bf_lo(h3.y));
            a3 += (bf_hi(h0.y) + bf_hi(h1.y)) + (bf_hi(h2.y) + bf_hi(h3.y));
            a4 += (bf_lo(h0.z) + bf_lo(h1.z)) + (bf_lo(h2.z) + bf_lo(h3.z));
            a5 += (bf_hi(h0.z) + bf_hi(h1.z)) + (bf_hi(h2.z) + bf_hi(h3.z));
            a6 += (bf_lo(h0.w) + bf_lo(h1.w)) + (bf_lo(h2.w) + bf_lo(h3.w));
            a7 += (bf_hi(h0.w) + bf_hi(h1.w)) + (bf_hi(h2.w) + bf_hi(h3.w));
        }
        for (; k < end; ++k) {
            int s = csr_src[k];
            uint4 h = H4[(long)s * TPN + lane];
            a0 += bf_lo(h.x); a1 += bf_hi(h.x);
            a2 += bf_lo(h.y); a3 += bf_hi(h.y);
            a4 += bf_lo(h.z); a5 += bf_hi(h.z);
            a6 += bf_lo(h.w); a7 += bf_hi(h.w);
        }
        float* vp = &vsh[nodeLocal][lane * 8];
        vp[0] = a0 * dd; vp[1] = a1 * dd; vp[2] = a2 * dd; vp[3] = a3 * dd;
        vp[4] = a4 * dd; vp[5] = a5 * dd; vp[6] = a6 * dd; vp[7] = a7 * dd;
        if (lane == 0) gsh[nodeLocal] = batch[node];
    } else {
        if (lane == 0) gsh[nodeLocal] = -1;
    }
    __syncthreads();

    if (threadIdx.x < 64) {
        const int ch = threadIdx.x;
        float acc = 0.f;
        int gprev = -1;
        for (int n = 0; n < NPB; ++n) {
            int g = gsh[n];
            if (g != gprev) {
                if (gprev >= 0) unsafeAtomicAdd(&psum[gprev * 64 + ch], acc);
                acc = 0.f;
                gprev = g;
            }
            if (g >= 0) acc += vsh[n][ch];
        }
        if (gprev >= 0) unsafeAtomicAdd(&psum[gprev * 64 + ch], acc);
    }
}

// ---------------- finalize: out = psum/cnt + b2 ----------------
__global__ __launch_bounds__(64) void k_pool2(const float* __restrict__ psum,
                                              const int* __restrict__ batch,
                                              const float* __restrict__ b2,
                                              float* __restrict__ out) {
    const int g = blockIdx.x;
    const int ch = threadIdx.x;
    int beg, end;
    {
        int lo = 0, hi = NN;
        while (lo < hi) { int mid = (lo + hi) >> 1; if (batch[mid] < g) lo = mid + 1; else hi = mid; }
        beg = lo;
        lo = beg; hi = NN;
        while (lo < hi) { int mid = (lo + hi) >> 1; if (batch[mid] < g + 1) lo = mid + 1; else hi = mid; }
        end = lo;
    }
    int cnt = end - beg;
    out[g * 64 + ch] = (cnt > 0) ? (psum[g * 64 + ch] / (float)cnt + b2[ch]) : 0.f;
}

extern "C" void kernel_launch(void* const* d_in, const int* in_sizes, int n_in,
                              void* d_out, int out_size, void* d_ws, size_t ws_size,
                              hipStream_t stream) {
    const float* x  = (const float*)d_in[0];
    const float* W1 = (const float*)d_in[1];
    const float* b1 = (const float*)d_in[2];
    const float* W2 = (const float*)d_in[3];
    const float* b2 = (const float*)d_in[4];
    const int* ei   = (const int*)d_in[5];
    const int* src  = (const int*)ei;
    const int* dst  = (const int*)(ei + NE);
    const int* batch = (const int*)d_in[6];
    float* out = (float*)d_out;

    char* p = (char*)d_ws;
    int* deg       = (int*)p;          p += (size_t)NN * 4;
    int* rowptr    = (int*)p;          p += (size_t)(NN + 4) * 4;
    int* cursor    = (int*)p;          p += (size_t)NN * 4;
    int* csr_src   = (int*)p;          p += (size_t)NE * 4;
    int* blockSums = (int*)p;          p += (size_t)64 * 4;
    float* dinv    = (float*)p;        p += (size_t)NN * 4;
    float* psum    = (float*)p;        p += (size_t)NG * 64 * 4;
    ushort_t* W1t  = (ushort_t*)p;     p += (size_t)128 * 128 * 2;
    ushort_t* W2t  = (ushort_t*)p;     p += (size_t)64 * 128 * 2;
    ushort_t* Hb   = (ushort_t*)p;     p += (size_t)NN * 128 * 2;   // gemm1 out (pre-scaled)
    ushort_t* Gb   = (ushort_t*)p;     p += (size_t)NN * 64 * 2;    // fused agg1+gemm2 out (pre-scaled)

    // ---- CSR build + prep ----
    k_prep<<<(NN + 255) / 256, 256, 0, stream>>>(W1, W2, deg, psum, W1t, W2t);
    k_hist<<<(NE + 255) / 256, 256, 0, stream>>>(dst, deg);
    k_scan1<<<SCAN_NB, SCAN_T, 0, stream>>>(deg, blockSums);
    k_scan3<<<SCAN_NB, SCAN_T, 0, stream>>>(deg, blockSums, rowptr, cursor, dinv);
    k_scatter<<<(NE + 255) / 256, 256, 0, stream>>>(src, dst, cursor, csr_src);

    // ---- layer 1 gemm ----
    k_gemm_mfma<<<(NN + 127) / 128, 256, 0, stream>>>(x, W1t, dinv, Hb);

    // ---- fused: agg1 (+bias,relu) + gemm2 (128->64) ----
    k_agg1g2<<<(NN + 31) / 32, 256, 0, stream>>>(rowptr, csr_src, dinv, Hb, b1, W2t, Gb);

    // ---- layer 2 aggregate fused with pooling ----
    k_agg2pool<<<(NN + 31) / 32, 256, 0, stream>>>(rowptr, csr_src, dinv, Gb, batch, psum);

    // ---- finalize ----
    k_pool2<<<NG, 64, 0, stream>>>(psum, batch, b2, out);
}